// Round 17
// baseline (47.278 us; speedup 1.0000x reference)
//
#include <hip/hip_runtime.h>

typedef _Float16 f16x8  __attribute__((ext_vector_type(8)));
typedef _Float16 f16x4  __attribute__((ext_vector_type(4)));
typedef __fp16   hf2    __attribute__((ext_vector_type(2)));
typedef float    f32x4  __attribute__((ext_vector_type(4)));
typedef float    f32x16 __attribute__((ext_vector_type(16)));

namespace {
constexpr int kN = 4, kL = 1024, kS = 1024, kH = 16, kE = 64, kD = 64;
constexpr int kRowF = kH * kE;     // 1024 floats: s-row stride of K and V
constexpr int KVB = 64;            // keys per LDS chunk
constexpr int NSB = kS / KVB / 2;  // 8 super-bodies (2 chunks each)
constexpr float SCL = 0.125f * 1.44269504088896340736f;  // 1/sqrt(E)*log2(e)
}

__device__ __forceinline__ unsigned pku(float a, float b) {
  union { hf2 h; unsigned u; } u;
  u.h = __builtin_amdgcn_cvt_pkrtz(a, b);
  return u.u;
}
__device__ __forceinline__ f16x4 pk4(float a, float b, float c, float d) {
  union { hf2 h2[2]; f16x4 v; } u;
  u.h2[0] = __builtin_amdgcn_cvt_pkrtz(a, b);
  u.h2[1] = __builtin_amdgcn_cvt_pkrtz(c, d);
  return u.v;
}
// cross-half-wave (lane ^32) max/sum via permlane32_swap (pure VALU)
__device__ __forceinline__ float xmax32(float t) {
  union { float f; unsigned u; } tu; tu.f = t;
  auto P = __builtin_amdgcn_permlane32_swap(tu.u, tu.u, false, false);
  union { unsigned u; float f; } a, b; a.u = P[0]; b.u = P[1];
  return fmaxf(a.f, b.f);
}
__device__ __forceinline__ float xsum32(float t) {
  union { float f; unsigned u; } tu; tu.f = t;
  auto P = __builtin_amdgcn_permlane32_swap(tu.u, tu.u, false, false);
  union { unsigned u; float f; } a, b; a.u = P[0]; b.u = P[1];
  return a.f + b.f;
}

// Detect all-zero mask/key_lengths: F[0] stays 0 iff every element is zero.
__global__ __launch_bounds__(256)
void flag_kernel(const float* __restrict__ M, const float* __restrict__ KLN,
                 unsigned* __restrict__ F)
{
  constexpr size_t nM = (size_t)kL * kS / 4, nK = (size_t)kN * kS / 4;
  unsigned any = 0;
  for (size_t i = (size_t)blockIdx.x * 256 + threadIdx.x; i < nM + nK;
       i += (size_t)gridDim.x * 256) {
    const f32x4 v = (i < nM) ? reinterpret_cast<const f32x4*>(M)[i]
                             : reinterpret_cast<const f32x4*>(KLN)[i - nM];
    #pragma unroll
    for (int r = 0; r < 4; ++r)
      any |= (__float_as_uint(v[r]) << 1);   // <<1 drops sign: -0 counts as 0
  }
  if (__any(any != 0) && (threadIdx.x & 63) == 0) atomicOr(F, 1u);
}

// R16 (47.1us) + QUAD-BUFFERED LDS, ONE BARRIER PER 2 CHUNKS: the 2-phase
// {stage; barrier; compute} lockstep was the residual overhead (m233-style);
// super-body b = {bar; write chunks 2b+2,2b+3; load 2b+4,2b+5; compute 2b;
// compute 2b+1} -- writes hit buffers (2b+2)&3,(2b+3)&3, reads (2b)&3,
// (2b+1)&3: disjoint mod 4, so one barrier per super-body is sound. Twice
// the independent work between barriers, half the sync/drain events. The
// per-chunk compute is BYTE-IDENTICAL to R16's verified math: 8-wave block,
// 256 q of one (n,h), role-split reg staging (waves 0-3 K, 4-7 V),
// half-decoupled chains (independent (m,lsum,acc) per 32-key half,
// flash-merged in registers), 32x32x16 MFMA, swapped scores S^T = K.Q^T
// (C/D col=lane&31=q, row=(reg&3)+8*(reg>>2)+4*(lane>>5)=s), XOR-swizzled
// conflict-free LDS, T12 cvt_pkrtz+permlane32_swap, defer-max THR=8,
// named accumulators only (rule #20: no address-taken hot state).
__global__ __launch_bounds__(512, 1)
void attn_fwd_kernel(const float* __restrict__ Q, const float* __restrict__ K,
                     const float* __restrict__ V, const float* __restrict__ M,
                     const float* __restrict__ KLN, float* __restrict__ O,
                     const unsigned* __restrict__ F)
{
  __shared__ _Float16 Ks[4][KVB * 64];
  __shared__ _Float16 Vt[4][kD * 64];

  const int tid  = threadIdx.x;
  const int lane = tid & 63;
  const int wave = tid >> 6;      // 0..7
  const int l31  = lane & 31;     // q within wave-tile; also s/d row in frags
  const int hi   = lane >> 5;
  const bool kRole = (wave < 4);  // staging role (wave-uniform)
  const int srow = (tid >> 4) & 15;
  const int scol = tid & 15;

  const int useMask = F ? (int)F[0] : 1;   // uniform

  // XCD swizzle (256 % 8 == 0 -> bijective)
  const int swz = ((blockIdx.x & 7) << 5) | (blockIdx.x >> 3);
  const int nh = swz >> 2, qb = swz & 3;
  const int h = nh & (kH - 1), n = nh >> 4;
  const int qrow = qb * 256 + wave * 32 + l31;

  const float* Kp = K + ((size_t)n * kS * kH + h) * kE;
  const float* Vp = V + ((size_t)n * kS * kH + h) * kD;
  const float* Lp = KLN + (size_t)n * kS;
  const float* Mp = M + (size_t)qrow * kS;

  // ---- hoisted Q B-frags (pre-scaled): qf[ec], k = 16*ec + 8*hi + j ----
  f16x8 qf[4];
  {
    const float* Qp = Q + ((size_t)((size_t)n * kL + qrow) * kH + h) * kE;
    #pragma unroll
    for (int ec = 0; ec < 4; ++ec) {
      const f32x4 a = *reinterpret_cast<const f32x4*>(Qp + 16*ec + 8*hi);
      const f32x4 b = *reinterpret_cast<const f32x4*>(Qp + 16*ec + 8*hi + 4);
      union { f16x4 h4[2]; f16x8 v; } u;
      u.h4[0] = pk4(a[0]*SCL, a[1]*SCL, a[2]*SCL, a[3]*SCL);
      u.h4[1] = pk4(b[0]*SCL, b[1]*SCL, b[2]*SCL, b[3]*SCL);
      qf[ec] = u.v;
    }
  }

  // ---- per-thread LDS constants (named scalars; verified round-6 math) ----
  const int kxor = (l31 & 7) << 1;
  const int d0 = l31,      d1 = 32 + l31;
  const int keyv0 = ((4*((d0>>2)&3) + (d0&3)) ^ (d0>>2)) & 15;
  const int keyv1 = ((4*((d1>>2)&3) + (d1&3)) ^ (d1>>2)) & 15;
  const int vrowb0 = d0 * 64, vrowb1 = d1 * 64;
  int hwv[4];
  #pragma unroll
  for (int jd = 0; jd < 4; ++jd)
    hwv[jd] = ((4*(scol & 3) + jd) ^ scol) & 15;

  const f32x16 z16 = {0,0,0,0, 0,0,0,0, 0,0,0,0, 0,0,0,0};
  f32x16 aA0 = z16, aA1 = z16, aB0 = z16, aB1 = z16;   // named accumulators
  float mA = -1e30f, lA = 0.f, mB = -1e30f, lB = 0.f;

  // ---- role-split staging (two chunks in flight: sg[0..3], sg[4..7]) ----
  f32x4 sg[8];
  auto load_one = [&](int sbase, int off) {
    if (kRole) {
      #pragma unroll
      for (int i = 0; i < 4; ++i)
        sg[off+i] = *reinterpret_cast<const f32x4*>(Kp + (size_t)(sbase + 16*i + srow) * kRowF + 4*scol);
    } else {
      #pragma unroll
      for (int js = 0; js < 4; ++js)
        sg[off+js] = *reinterpret_cast<const f32x4*>(Vp + (size_t)(sbase + 4*srow + js) * kRowF + 4*scol);
    }
  };
  auto write_one = [&](int buf, int off) {
    if (kRole) {
      #pragma unroll
      for (int i = 0; i < 4; ++i) {
        const int s = 16*i + srow;
        *reinterpret_cast<f16x4*>(&Ks[buf][s*64 + ((scol ^ ((s & 7) << 1)) << 2)]) =
            pk4(sg[off+i][0], sg[off+i][1], sg[off+i][2], sg[off+i][3]);
      }
    } else {
      #pragma unroll
      for (int jd = 0; jd < 4; ++jd) {
        const int d = 4*scol + jd;
        *reinterpret_cast<f16x4*>(&Vt[buf][d*64 + ((srow ^ hwv[jd]) << 2)]) =
            pk4(sg[off+0][jd], sg[off+1][jd], sg[off+2][jd], sg[off+3][jd]);
      }
    }
  };

  // one 32-key half: logits -> per-half online softmax -> pack -> PV.
  // Accumulators passed as INDIVIDUAL references (never address-taken).
  auto half_tail = [&](const f32x16& cc, int hf, int s0h, int vbuf,
                       float& mrun, float& lsum, f32x16& a0, f32x16& a1) {
    float x[16];
    if (useMask) {
      #pragma unroll
      for (int m = 0; m < 4; ++m) {
        const f32x4 mv = *reinterpret_cast<const f32x4*>(Mp + s0h + 8*m + 4*hi);
        const f32x4 lv = *reinterpret_cast<const f32x4*>(Lp + s0h + 8*m + 4*hi);
        #pragma unroll
        for (int r = 0; r < 4; ++r)
          x[4*m+r] = fmaf(mv[r] + lv[r], SCL, cc[4*m+r]);
      }
    } else {
      #pragma unroll
      for (int r = 0; r < 16; ++r) x[r] = cc[r];
    }
    float mx[8];
    #pragma unroll
    for (int i = 0; i < 8; ++i) mx[i] = fmaxf(x[i], x[i+8]);
    #pragma unroll
    for (int w = 4; w >= 1; w >>= 1)
      #pragma unroll
      for (int i = 0; i < w; ++i) mx[i] = fmaxf(mx[i], mx[i+w]);
    const float tmax = xmax32(mx[0]);

    if (!__all(tmax <= mrun + 8.f)) {        // defer-max THR=8 (log2)
      const float mnew = fmaxf(mrun, tmax);
      const float rs = __builtin_amdgcn_exp2f(mrun - mnew);
      mrun = mnew; lsum *= rs;
      a0 *= rs; a1 *= rs;
    }
    #pragma unroll
    for (int i = 0; i < 16; ++i)
      x[i] = __builtin_amdgcn_exp2f(x[i] - mrun);
    float s8[8];
    #pragma unroll
    for (int i = 0; i < 8; ++i) s8[i] = x[i] + x[i+8];
    #pragma unroll
    for (int w = 4; w >= 1; w >>= 1)
      #pragma unroll
      for (int i = 0; i < w; ++i) s8[i] += s8[i+w];
    lsum += s8[0];

    // pack P -> 2 PV B-frags via cvt_pk + permlane32_swap (verified)
    f16x8 pf0, pf1;
    {
      const unsigned k0 = pku(x[0], x[1]);
      const unsigned k1 = pku(x[2], x[3]);
      const unsigned w0 = pku(x[4], x[5]);
      const unsigned w1 = pku(x[6], x[7]);
      auto X = __builtin_amdgcn_permlane32_swap(k0, w0, false, false);
      auto Y = __builtin_amdgcn_permlane32_swap(k1, w1, false, false);
      union { unsigned u[4]; f16x8 v; } pu;
      pu.u[0] = X[0]; pu.u[1] = Y[0]; pu.u[2] = X[1]; pu.u[3] = Y[1];
      pf0 = pu.v;
    }
    {
      const unsigned k0 = pku(x[8],  x[9]);
      const unsigned k1 = pku(x[10], x[11]);
      const unsigned w0 = pku(x[12], x[13]);
      const unsigned w1 = pku(x[14], x[15]);
      auto X = __builtin_amdgcn_permlane32_swap(k0, w0, false, false);
      auto Y = __builtin_amdgcn_permlane32_swap(k1, w1, false, false);
      union { unsigned u[4]; f16x8 v; } pu;
      pu.u[0] = X[0]; pu.u[1] = Y[0]; pu.u[2] = X[1]; pu.u[3] = Y[1];
      pf1 = pu.v;
    }
    __builtin_amdgcn_s_setprio(1);
    #pragma unroll
    for (int sc = 0; sc < 2; ++sc) {
      const f16x8 pf = (sc == 0) ? pf0 : pf1;
      const int scg = hf*2 + sc;
      {
        const int sl0 = ((scg << 2) + (hi << 1)) ^ keyv0;
        union { f16x4 h4[2]; f16x8 v; } vu;
        vu.h4[0] = *reinterpret_cast<const f16x4*>(&Vt[vbuf][vrowb0 + (sl0 << 2)]);
        vu.h4[1] = *reinterpret_cast<const f16x4*>(&Vt[vbuf][vrowb0 + ((sl0 ^ 1) << 2)]);
        a0 = __builtin_amdgcn_mfma_f32_32x32x16_f16(vu.v, pf, a0, 0, 0, 0);
      }
      {
        const int sl1 = ((scg << 2) + (hi << 1)) ^ keyv1;
        union { f16x4 h4[2]; f16x8 v; } vu;
        vu.h4[0] = *reinterpret_cast<const f16x4*>(&Vt[vbuf][vrowb1 + (sl1 << 2)]);
        vu.h4[1] = *reinterpret_cast<const f16x4*>(&Vt[vbuf][vrowb1 + ((sl1 ^ 1) << 2)]);
        a1 = __builtin_amdgcn_mfma_f32_32x32x16_f16(vu.v, pf, a1, 0, 0, 0);
      }
    }
    __builtin_amdgcn_s_setprio(0);
  };

  // full 64-key chunk: QK for both halves, then the two decoupled chains
  auto do_chunk = [&](int buf, int s0) {
    f32x16 ccA = z16, ccB = z16;
    __builtin_amdgcn_s_setprio(1);
    #pragma unroll
    for (int ec = 0; ec < 4; ++ec) {
      const f16x8 kfA = *reinterpret_cast<const f16x8*>(
          &Ks[buf][l31*64 + ((((ec << 2) + (hi << 1)) ^ kxor) << 2)]);
      ccA = __builtin_amdgcn_mfma_f32_32x32x16_f16(kfA, qf[ec], ccA, 0, 0, 0);
    }
    #pragma unroll
    for (int ec = 0; ec < 4; ++ec) {
      const f16x8 kfB = *reinterpret_cast<const f16x8*>(
          &Ks[buf][l31*64 + 2048 + ((((ec << 2) + (hi << 1)) ^ kxor) << 2)]);
      ccB = __builtin_amdgcn_mfma_f32_32x32x16_f16(kfB, qf[ec], ccB, 0, 0, 0);
    }
    __builtin_amdgcn_s_setprio(0);
    half_tail(ccA, 0, s0,      buf, mA, lA, aA0, aA1);
    half_tail(ccB, 1, s0 + 32, buf, mB, lB, aB0, aB1);
  };

  // ---- prologue: chunks 0,1 staged; chunks 2,3 in flight ----
  load_one(0, 0);        load_one(KVB, 4);
  write_one(0, 0);       write_one(1, 4);
  load_one(2*KVB, 0);    load_one(3*KVB, 4);

  // ---- main loop: 8 super-bodies, ONE barrier per 2 chunks ----
  for (int b = 0; b < NSB; ++b) {
    __syncthreads();
    if (b + 1 < NSB) {                 // write chunks 2b+2, 2b+3
      write_one((2*b + 2) & 3, 0);
      write_one((2*b + 3) & 3, 4);
    }
    if (b + 2 < NSB) {                 // load chunks 2b+4, 2b+5
      load_one((2*b + 4) * KVB, 0);
      load_one((2*b + 5) * KVB, 4);
    }
    do_chunk((2*b) & 3,     (2*b) * KVB);
    do_chunk((2*b + 1) & 3, (2*b + 1) * KVB);
  }

  // ---- epilogue: in-register flash-merge of the two halves, store ----
  lA = xsum32(lA);
  lB = xsum32(lB);
  const float mM = fmaxf(mA, mB);
  const float wA = __builtin_amdgcn_exp2f(mA - mM);
  const float wB = __builtin_amdgcn_exp2f(mB - mM);
  const float inv = 1.f / (lA * wA + lB * wB);
  float* Op = O + (((size_t)n * kL + qrow) * kH + h) * kD;
  #pragma unroll
  for (int m = 0; m < 4; ++m) {
    f32x4 o;
    #pragma unroll
    for (int r = 0; r < 4; ++r)
      o[r] = (aA0[4*m+r] * wA + aB0[4*m+r] * wB) * inv;
    *reinterpret_cast<f32x4*>(Op + 8*m + 4*hi) = o;
  }
  #pragma unroll
  for (int m = 0; m < 4; ++m) {
    f32x4 o;
    #pragma unroll
    for (int r = 0; r < 4; ++r)
      o[r] = (aA1[4*m+r] * wA + aB1[4*m+r] * wB) * inv;
    *reinterpret_cast<f32x4*>(Op + 32 + 8*m + 4*hi) = o;
  }
}

extern "C" void kernel_launch(void* const* d_in, const int* in_sizes, int n_in,
                              void* d_out, int out_size, void* d_ws, size_t ws_size,
                              hipStream_t stream) {
  const float* Q   = (const float*)d_in[0];
  const float* K   = (const float*)d_in[1];
  const float* V   = (const float*)d_in[2];
  const float* M   = (const float*)d_in[3];
  const float* KLN = (const float*)d_in[4];
  float* O = (float*)d_out;

  unsigned* F = nullptr;
  if (ws_size >= sizeof(unsigned)) {
    F = (unsigned*)d_ws;
    hipMemsetAsync(F, 0, sizeof(unsigned), stream);
    flag_kernel<<<dim3(1024), dim3(256), 0, stream>>>(M, KLN, F);
  }

  dim3 grid(kN * kH * (kL / 256));  // 256 blocks (256 q-rows each)
  dim3 block(512);                  // 8 waves, 32 queries each
  attn_fwd_kernel<<<grid, block, 0, stream>>>(Q, K, V, M, KLN, O, F);
}